// Round 1
// 776.340 us; speedup vs baseline: 1.1450x; 1.1450x over previous
//
#include <hip/hip_runtime.h>

#define NB   256
#define NT   512
#define DHX  100   // DX
#define DHZ  100   // DZ
#define DOUT 500
#define WIN  8     // steps per sync window
#define RING 16    // h1 ring depth (2 windows)

__device__ __forceinline__ float sgm(float v) { return 1.f / (1.f + __expf(-v)); }
__device__ __forceinline__ float tnh(float v) {
    v = fminf(fmaxf(v, -15.f), 15.f);
    float e = __expf(2.f * v);
    return (e - 1.f) / (e + 1.f);
}
__device__ __forceinline__ float sftp(float v) {
    return fmaxf(v, 0.f) + __logf(1.f + __expf(-fabsf(v)));
}
// v_readlane: broadcast lane k's value to a wave-uniform (SGPR) scalar.
__device__ __forceinline__ float rdlane(float v, int k) {
    return __uint_as_float(__builtin_amdgcn_readlane(__float_as_uint(v), (unsigned)k));
}

// One block (128 threads = 2 waves) per batch element.
// wave0: h1 recurrence (dz MLP -> z reparam -> GRU1) + z outputs.
// wave1: h2 recurrence (GRU2 over x) + dx MLP + x outputs, one 8-step WINDOW
//        behind wave0 (reads h1 from a 16-deep LDS ring).
// Recurrent state (h1/h2, 10-wide) and MLP hiddens (20-wide) live as
// wave-uniform scalars via v_readlane broadcasts -- no LDS round trips on
// the chain except the unavoidable 100-wide z_t all-to-all (zbuf) and the
// latency-hidden xbuf double buffer. Gate gathers use ds_bpermute shuffles.
__global__ __launch_bounds__(128, 1) void arfssm(
    const float* __restrict__ x, const float* __restrict__ eps,
    const float* __restrict__ W_ih1, const float* __restrict__ W_hh1,
    const float* __restrict__ b_ih1, const float* __restrict__ b_hh1,
    const float* __restrict__ W_ih2, const float* __restrict__ W_hh2,
    const float* __restrict__ b_ih2, const float* __restrict__ b_hh2,
    const float* __restrict__ dz_W1, const float* __restrict__ dz_b1,
    const float* __restrict__ dz_Wloc, const float* __restrict__ dz_bloc,
    const float* __restrict__ dz_Wscale, const float* __restrict__ dz_bscale,
    const float* __restrict__ dx_W1, const float* __restrict__ dx_b1,
    const float* __restrict__ dx_Wloc, const float* __restrict__ dx_bloc,
    const float* __restrict__ dx_Wscale, const float* __restrict__ dx_bscale,
    const float* __restrict__ h1_0, const float* __restrict__ h2_0,
    float* __restrict__ out)
{
    __shared__ __align__(16) float h1d[RING][12];  // h1 ring: slot k = h1 after k steps (mod 16)
    __shared__ __align__(16) float xbuf[2][104];   // wave1-private x row double buffer
    __shared__ __align__(16) float zbuf[104];      // wave0-private z_t

    const int tid = threadIdx.x;
    const int b   = blockIdx.x;

    if (tid < 64) {
        // ============================ WAVE 0 ============================
        const int l = tid;

        // ---- per-lane weight preload ----
        float wdz1[10]; float bdz1 = 0.f;
        #pragma unroll
        for (int k = 0; k < 10; ++k) wdz1[k] = 0.f;
        if (l < 20) {
            #pragma unroll
            for (int k = 0; k < 10; ++k) wdz1[k] = dz_W1[l * 10 + k];
            bdz1 = dz_b1[l];
        }
        float wzl1[20], wzs1[20];
        #pragma unroll
        for (int k = 0; k < 20; ++k) { wzl1[k] = dz_Wloc[l * 20 + k]; wzs1[k] = dz_Wscale[l * 20 + k]; }
        const float bzl1 = dz_bloc[l], bzs1 = dz_bscale[l];
        float wzl2[20], wzs2[20]; float bzl2 = 0.f, bzs2 = 0.f;
        #pragma unroll
        for (int k = 0; k < 20; ++k) { wzl2[k] = 0.f; wzs2[k] = 0.f; }
        if (l < 36) {
            const int j2 = l + 64;
            #pragma unroll
            for (int k = 0; k < 20; ++k) { wzl2[k] = dz_Wloc[j2 * 20 + k]; wzs2[k] = dz_Wscale[j2 * 20 + k]; }
            bzl2 = dz_bloc[j2]; bzs2 = dz_bscale[j2];
        }
        const int gi_i = l >> 1, gi_h = l & 1;
        float wA[52]; float bih_p = 0.f, bhh_p = 0.f; float whh_p[10];
        #pragma unroll
        for (int k = 0; k < 52; ++k) wA[k] = 0.f;
        #pragma unroll
        for (int k = 0; k < 10; ++k) whh_p[k] = 0.f;
        if (l < 60) {
            const int k0 = gi_h ? 52 : 0;
            const int kn = gi_h ? 48 : 52;
            #pragma unroll
            for (int k = 0; k < 52; ++k) if (k < kn) wA[k] = W_ih1[gi_i * 100 + k0 + k];
            bih_p = b_ih1[gi_i];
            bhh_p = b_hh1[gi_i];
            #pragma unroll
            for (int k = 0; k < 10; ++k) whh_p[k] = W_hh1[gi_i * 10 + k];
        }

        // ---- state: h1 as wave-uniform scalars + per-lane copy in lanes 0..9 ----
        float hs[10];
        #pragma unroll
        for (int k = 0; k < 10; ++k) hs[k] = h1_0[k];
        float h1own = (l < 10) ? h1_0[l] : 0.f;
        if (l < 4) zbuf[100 + l] = 0.f;
        float e1c = eps[(size_t)b * NT * DHZ + l];
        float e2c = (l < 36) ? eps[(size_t)b * NT * DHZ + 64 + l] : 0.f;

        for (int w = 0; w < 64; ++w) {
            #pragma unroll 2
            for (int i = 0; i < 8; ++i) {
                const int t   = 8 * w + i;
                const int wsl = (t + 1) & (RING - 1);

                // dz hidden: lane l<20 computes hdz[l] from uniform h1
                float hv = bdz1;
                #pragma unroll
                for (int k = 0; k < 10; ++k) hv = fmaf(wdz1[k], hs[k], hv);
                hv = fmaxf(hv, 0.f);
                // broadcast 20 hidden values to uniforms (replaces LDS round trip)
                float hd[20];
                #pragma unroll
                for (int k = 0; k < 20; ++k) hd[k] = rdlane(hv, k);

                // prefetch eps(t+1)
                const int tn = (t + 1 < NT) ? (t + 1) : t;
                const float* ern = eps + ((size_t)b * NT + tn) * DHZ;
                float e1n = ern[l];
                float e2n = (l < 36) ? ern[64 + l] : 0.f;

                // z heads (same accumulation order as before)
                float vl1 = bzl1, vs1 = bzs1, vl2 = bzl2, vs2 = bzs2;
                #pragma unroll
                for (int k = 0; k < 20; ++k) {
                    vl1 = fmaf(wzl1[k], hd[k], vl1); vs1 = fmaf(wzs1[k], hd[k], vs1);
                    vl2 = fmaf(wzl2[k], hd[k], vl2); vs2 = fmaf(wzs2[k], hd[k], vs2);
                }
                float sp1 = sftp(vs1), sp2 = sftp(vs2);
                float zt1 = fmaf(sp1, e1c, vl1);
                float zt2 = fmaf(sp2, e2c, vl2);
                zbuf[l] = zt1;
                if (l < 36) zbuf[64 + l] = zt2;
                __builtin_amdgcn_wave_barrier();

                const size_t ob = ((size_t)b * NT + t) * DOUT;
                out[ob + 200 + l] = vl1; out[ob + 300 + l] = sp1; out[ob + 400 + l] = zt1;
                if (l < 36) { out[ob + 264 + l] = vl2; out[ob + 364 + l] = sp2; out[ob + 464 + l] = zt2; }
                e1c = e1n; e2c = e2n;

                // gi1 = W_ih1 @ z_t (split-K lane pairs over zbuf)
                const float4* z4 = (const float4*)zbuf;
                const int b4 = gi_h ? 13 : 0;
                float a0 = 0.f, a1 = 0.f, a2 = 0.f, a3 = 0.f;
                #pragma unroll
                for (int q = 0; q < 13; ++q) {
                    float4 zz = z4[b4 + q];
                    a0 = fmaf(wA[4*q+0], zz.x, a0);
                    a1 = fmaf(wA[4*q+1], zz.y, a1);
                    a2 = fmaf(wA[4*q+2], zz.z, a2);
                    a3 = fmaf(wA[4*q+3], zz.w, a3);
                }
                float acc = (a0 + a1) + (a2 + a3);
                acc += __shfl_xor(acc, 1, 64);           // both lanes of pair hold full gi1[i]
                float gh = bhh_p;                         // gh1[i] from uniform h1 (both lanes)
                #pragma unroll
                for (int k = 0; k < 10; ++k) gh = fmaf(whh_p[k], hs[k], gh);
                float gih  = acc + bih_p;
                float gsum = gih + gh;

                // gate gathers via bpermute: row l from lane 2l, row l+10 from 2l+20,
                // row l+20 (gi and gh separately) from 2l+40
                float s_r  = __shfl(gsum, 2 * l,      64);
                float s_u  = __shfl(gsum, 2 * l + 20, 64);
                float g_in = __shfl(gih,  2 * l + 40, 64);
                float g_hn = __shfl(gh,   2 * l + 40, 64);
                float r = sgm(s_r), u = sgm(s_u);
                float n = tnh(fmaf(r, g_hn, g_in));
                float h1n_v = (1.f - u) * n + u * h1own;  // valid in lanes 0..9

                if (l < 10) h1d[wsl][l] = h1n_v;          // handoff to wave1 (off chain)
                #pragma unroll
                for (int k = 0; k < 10; ++k) hs[k] = rdlane(h1n_v, k);
                h1own = h1n_v;
            }
            __syncthreads();   // end of window w
        }
        __syncthreads();       // window 64 (wave1 epilogue window)
    } else {
        // ============================ WAVE 1 ============================
        const int l = tid - 64;

        // ---- per-lane weight preload ----
        float wdx1[20]; float bdx1 = 0.f;
        #pragma unroll
        for (int k = 0; k < 20; ++k) wdx1[k] = 0.f;
        if (l < 20) {
            #pragma unroll
            for (int k = 0; k < 20; ++k) wdx1[k] = dx_W1[l * 20 + k];
            bdx1 = dx_b1[l];
        }
        float wxl1[20], wxs1[20];
        #pragma unroll
        for (int k = 0; k < 20; ++k) { wxl1[k] = dx_Wloc[l * 20 + k]; wxs1[k] = dx_Wscale[l * 20 + k]; }
        const float bxl1 = dx_bloc[l], bxs1 = dx_bscale[l];
        float wxl2[20], wxs2[20]; float bxl2 = 0.f, bxs2 = 0.f;
        #pragma unroll
        for (int k = 0; k < 20; ++k) { wxl2[k] = 0.f; wxs2[k] = 0.f; }
        if (l < 36) {
            const int j2 = l + 64;
            #pragma unroll
            for (int k = 0; k < 20; ++k) { wxl2[k] = dx_Wloc[j2 * 20 + k]; wxs2[k] = dx_Wscale[j2 * 20 + k]; }
            bxl2 = dx_bloc[j2]; bxs2 = dx_bscale[j2];
        }
        const int gi_i = l >> 1, gi_h = l & 1;
        float wB[52]; float bih_p = 0.f, bhh_p = 0.f; float whh_p[10];
        #pragma unroll
        for (int k = 0; k < 52; ++k) wB[k] = 0.f;
        #pragma unroll
        for (int k = 0; k < 10; ++k) whh_p[k] = 0.f;
        if (l < 60) {
            const int k0 = gi_h ? 52 : 0;
            const int kn = gi_h ? 48 : 52;
            #pragma unroll
            for (int k = 0; k < 52; ++k) if (k < kn) wB[k] = W_ih2[gi_i * 100 + k0 + k];
            bih_p = b_ih2[gi_i];
            bhh_p = b_hh2[gi_i];
            #pragma unroll
            for (int k = 0; k < 10; ++k) whh_p[k] = W_hh2[gi_i * 10 + k];
        }

        // ---- state: h2 as wave-uniform scalars + per-lane copy in lanes 0..9 ----
        float hs2[10];
        #pragma unroll
        for (int k = 0; k < 10; ++k) hs2[k] = h2_0[k];
        float h2own = (l < 10) ? h2_0[l] : 0.f;

        // ---- prologue: x row 0 -> xbuf[0], row 1 -> vh ----
        if (l < 4) { xbuf[0][100 + l] = 0.f; xbuf[1][100 + l] = 0.f; }
        float4 vh = make_float4(0.f, 0.f, 0.f, 0.f);
        if (l < 25) {
            const float4* xr0 = (const float4*)(x + (size_t)b * NT * DHX);
            const float4* xr1 = (const float4*)(x + ((size_t)b * NT + 1) * DHX);
            float4 v0 = xr0[l];
            vh = xr1[l];
            *((float4*)&xbuf[0][0] + l) = v0;
        }

        __syncthreads();       // window 0 (wave0 fills h1 slots 1..8)
        for (int w = 1; w < 65; ++w) {
            #pragma unroll 2
            for (int i = 0; i < 8; ++i) {
                const int t = 8 * (w - 1) + i;

                // publish x(t+1); prefetch x(t+2)
                if (l < 25) *((float4*)&xbuf[(t + 1) & 1][0] + l) = vh;
                {
                    const int tn = (t + 2 < NT) ? (t + 2) : (NT - 1);
                    if (l < 25) vh = ((const float4*)(x + ((size_t)b * NT + tn) * DHX))[l];
                }

                // issue h1n(t) ring read early; latency hides under GRU2 FMAs
                const int hsl = (t + 1) & (RING - 1);
                float4 ha = *(const float4*)&h1d[hsl][0];
                float4 hb = *(const float4*)&h1d[hsl][4];
                float h8 = h1d[hsl][8], h9 = h1d[hsl][9];

                // GRU2 gi2 from xbuf[t&1] (published last step -> data ready)
                const float4* x4 = (const float4*)&xbuf[t & 1][0];
                const int b4 = gi_h ? 13 : 0;
                float a0 = 0.f, a1 = 0.f, a2 = 0.f, a3 = 0.f;
                #pragma unroll
                for (int q = 0; q < 13; ++q) {
                    float4 xx = x4[b4 + q];
                    a0 = fmaf(wB[4*q+0], xx.x, a0);
                    a1 = fmaf(wB[4*q+1], xx.y, a1);
                    a2 = fmaf(wB[4*q+2], xx.z, a2);
                    a3 = fmaf(wB[4*q+3], xx.w, a3);
                }
                float acc = (a0 + a1) + (a2 + a3);
                acc += __shfl_xor(acc, 1, 64);
                float gh = bhh_p;                        // gh2[i] from uniform h2 (pre-update)
                #pragma unroll
                for (int k = 0; k < 10; ++k) gh = fmaf(whh_p[k], hs2[k], gh);
                float gih  = acc + bih_p;
                float gsum = gih + gh;
                // issue gate gathers now; their latency hides under the dx MLP
                float s_r  = __shfl(gsum, 2 * l,      64);
                float s_u  = __shfl(gsum, 2 * l + 20, 64);
                float g_in = __shfl(gih,  2 * l + 40, 64);
                float g_hn = __shfl(gh,   2 * l + 40, 64);

                // dx MLP for step t: h1n(t) from ring, h2_shift(t) = hs2 (pre-update)
                float hv = bdx1;
                hv = fmaf(wdx1[0], ha.x, hv); hv = fmaf(wdx1[1], ha.y, hv);
                hv = fmaf(wdx1[2], ha.z, hv); hv = fmaf(wdx1[3], ha.w, hv);
                hv = fmaf(wdx1[4], hb.x, hv); hv = fmaf(wdx1[5], hb.y, hv);
                hv = fmaf(wdx1[6], hb.z, hv); hv = fmaf(wdx1[7], hb.w, hv);
                hv = fmaf(wdx1[8], h8, hv);   hv = fmaf(wdx1[9], h9, hv);
                #pragma unroll
                for (int k = 0; k < 10; ++k) hv = fmaf(wdx1[10 + k], hs2[k], hv);
                hv = fmaxf(hv, 0.f);
                float hx[20];
                #pragma unroll
                for (int k = 0; k < 20; ++k) hx[k] = rdlane(hv, k);

                float vl1 = bxl1, vs1 = bxs1, vl2 = bxl2, vs2 = bxs2;
                #pragma unroll
                for (int k = 0; k < 20; ++k) {
                    vl1 = fmaf(wxl1[k], hx[k], vl1); vs1 = fmaf(wxs1[k], hx[k], vs1);
                    vl2 = fmaf(wxl2[k], hx[k], vl2); vs2 = fmaf(wxs2[k], hx[k], vs2);
                }
                const size_t ob = ((size_t)b * NT + t) * DOUT;
                out[ob + l]       = vl1;
                out[ob + 100 + l] = sftp(vs1);
                if (l < 36) { out[ob + 64 + l] = vl2; out[ob + 164 + l] = sftp(vs2); }

                // gates + h2 update
                float r = sgm(s_r), u = sgm(s_u);
                float n = tnh(fmaf(r, g_hn, g_in));
                float h2n_v = (1.f - u) * n + u * h2own;  // valid in lanes 0..9
                #pragma unroll
                for (int k = 0; k < 10; ++k) hs2[k] = rdlane(h2n_v, k);
                h2own = h2n_v;
            }
            __syncthreads();   // end of window w
        }
    }
}

extern "C" void kernel_launch(void* const* d_in, const int* in_sizes, int n_in,
                              void* d_out, int out_size, void* d_ws, size_t ws_size,
                              hipStream_t stream) {
    (void)in_sizes; (void)n_in; (void)out_size; (void)d_ws; (void)ws_size;
    const float* x         = (const float*)d_in[0];
    const float* eps       = (const float*)d_in[1];
    const float* W_ih1     = (const float*)d_in[2];
    const float* W_hh1     = (const float*)d_in[3];
    const float* b_ih1     = (const float*)d_in[4];
    const float* b_hh1     = (const float*)d_in[5];
    const float* W_ih2     = (const float*)d_in[6];
    const float* W_hh2     = (const float*)d_in[7];
    const float* b_ih2     = (const float*)d_in[8];
    const float* b_hh2     = (const float*)d_in[9];
    const float* dz_W1     = (const float*)d_in[10];
    const float* dz_b1     = (const float*)d_in[11];
    const float* dz_Wloc   = (const float*)d_in[12];
    const float* dz_bloc   = (const float*)d_in[13];
    const float* dz_Wscale = (const float*)d_in[14];
    const float* dz_bscale = (const float*)d_in[15];
    const float* dx_W1     = (const float*)d_in[16];
    const float* dx_b1     = (const float*)d_in[17];
    const float* dx_Wloc   = (const float*)d_in[18];
    const float* dx_bloc   = (const float*)d_in[19];
    const float* dx_Wscale = (const float*)d_in[20];
    const float* dx_bscale = (const float*)d_in[21];
    const float* h1_0      = (const float*)d_in[22];
    const float* h2_0      = (const float*)d_in[23];

    arfssm<<<NB, 128, 0, stream>>>(x, eps, W_ih1, W_hh1, b_ih1, b_hh1,
                                   W_ih2, W_hh2, b_ih2, b_hh2,
                                   dz_W1, dz_b1, dz_Wloc, dz_bloc, dz_Wscale, dz_bscale,
                                   dx_W1, dx_b1, dx_Wloc, dx_bloc, dx_Wscale, dx_bscale,
                                   h1_0, h2_0, (float*)d_out);
}